// Round 4
// baseline (259.794 us; speedup 1.0000x reference)
//
#include <hip/hip_runtime.h>

// x: (16,1,1536,1536) fp32, kernel_size=3. Keep only first-argmax value per
// non-overlapping 3x3 block (row-major tie-break), zero the rest.
//
// Structure (round 2, confirmed ~HBM-bound): 256-thread WG stages a 6x1536
// tile (36 KB LDS, 4 WG/CU), computes per-block argmax-keep in registers,
// writes back in place, streams out coalesced.
// Round 3/4 deltas:
//  - phase 1 uses global_load_lds width=16 (async direct-to-LDS, no VGPR
//    round-trip; compiler never auto-emits this).
//  - phase 3 uses non-temporal stores via native ext_vector_type(4)
//    (__builtin_nontemporal_store rejects HIP_vector_type).

#define IMG_H 1536
#define IMG_W 1536
#define N_IMG 16
#define TILE_ROWS 6                       // 2 block-rows
#define TILE_F (TILE_ROWS * IMG_W)        // 9216 floats = 36 KB
#define TILE_V (TILE_F / 4)               // 2304 float4
#define V_PER_T (TILE_V / 256)            // 9 float4 per thread per phase
#define TILES_PER_IMG (IMG_H / TILE_ROWS) // 256

typedef float __attribute__((ext_vector_type(4))) f32x4;
typedef __attribute__((address_space(3))) uint32_t lds_word_t;
typedef const __attribute__((address_space(1))) uint32_t glb_word_t;

__global__ __launch_bounds__(256) void pool_nms_kernel(const float* __restrict__ x,
                                                       float* __restrict__ out) {
    __shared__ float lds[TILE_F];

    const int wg = blockIdx.x;
    const int n  = wg >> 8;                 // / TILES_PER_IMG
    const int tr = wg & (TILES_PER_IMG - 1);
    const size_t base = (size_t)n * (IMG_H * (size_t)IMG_W)
                      + (size_t)(tr * TILE_ROWS) * IMG_W;
    const int t = threadIdx.x;

    // Phase 1: async global -> LDS, 16B per lane, linear layout.
    // Per wave: LDS dest = wave-uniform base + lane*16 (HW requirement) --
    // satisfied since float4 #(t + k*256) is lane-contiguous.
    const f32x4* xin = (const f32x4*)(x + base);
#pragma unroll
    for (int k = 0; k < V_PER_T; ++k) {
        const int v = t + k * 256;
        __builtin_amdgcn_global_load_lds((glb_word_t*)(xin + v),
                                         (lds_word_t*)(lds + v * 4),
                                         16, 0, 0);
    }
    __syncthreads();   // compiler drains vmcnt(0) before s_barrier

    // Phase 2: each thread owns 4 consecutive 3x3 blocks in one block-row.
    const int br = t >> 7;        // 0..1  block-row within tile
    const int g  = t & 127;       // group of 4 blocks along W
    float row[3][12];
#pragma unroll
    for (int r = 0; r < 3; ++r) {
        const float* p = lds + (br * 3 + r) * IMG_W + g * 12;
#pragma unroll
        for (int j = 0; j < 3; ++j) {
            f32x4 v4 = *(const f32x4*)(p + j * 4);
            row[r][j * 4 + 0] = v4.x;
            row[r][j * 4 + 1] = v4.y;
            row[r][j * 4 + 2] = v4.z;
            row[r][j * 4 + 3] = v4.w;
        }
    }

    float o[3][12];
#pragma unroll
    for (int s = 0; s < 4; ++s) {
        const int c0 = s * 3;
        float best = row[0][c0];
        int bi = 0;
#pragma unroll
        for (int r = 0; r < 3; ++r) {
#pragma unroll
            for (int c = 0; c < 3; ++c) {
                const float vv = row[r][c0 + c];
                if (vv > best) { best = vv; bi = r * 3 + c; }
            }
        }
#pragma unroll
        for (int r = 0; r < 3; ++r) {
#pragma unroll
            for (int c = 0; c < 3; ++c) {
                o[r][c0 + c] = ((r * 3 + c) == bi) ? row[r][c0 + c] : 0.0f;
            }
        }
    }

    // write back in place (cells are exclusive to this thread)
#pragma unroll
    for (int r = 0; r < 3; ++r) {
        float* p = lds + (br * 3 + r) * IMG_W + g * 12;
#pragma unroll
        for (int j = 0; j < 3; ++j) {
            f32x4 v4 = { o[r][j * 4 + 0], o[r][j * 4 + 1],
                         o[r][j * 4 + 2], o[r][j * 4 + 3] };
            *(f32x4*)(p + j * 4) = v4;
        }
    }
    __syncthreads();

    // Phase 3: coalesced LDS -> global, non-temporal (write-once stream)
    f32x4* po = (f32x4*)(out + base);
#pragma unroll
    for (int k = 0; k < V_PER_T; ++k) {
        const int v = t + k * 256;
        __builtin_nontemporal_store(((const f32x4*)lds)[v], po + v);
    }
}

extern "C" void kernel_launch(void* const* d_in, const int* in_sizes, int n_in,
                              void* d_out, int out_size, void* d_ws, size_t ws_size,
                              hipStream_t stream) {
    const float* x = (const float*)d_in[0];
    float* out = (float*)d_out;
    const int n_wg = N_IMG * TILES_PER_IMG;   // 4096
    pool_nms_kernel<<<n_wg, 256, 0, stream>>>(x, out);
}

// Round 5
// 258.684 us; speedup vs baseline: 1.0043x; 1.0043x over previous
//
#include <hip/hip_runtime.h>
#include <math.h>

// x: (16,1,1536,1536) fp32, k=3. Keep first-argmax per non-overlapping 3x3
// block, zero the rest.
//
// Round-4 lesson: LDS-staged version ran 90us @ 2.5 TB/s -- the two
// barrier+vmcnt(0) drains per WG serialize the stream (harness fill kernel
// does 6.7 TB/s with no barriers). This version is barrier-free and LDS-free:
// each wave owns 3 rows x 256 cols; per-lane float4 loads are perfectly
// coalesced; the 2 neighbor columns each side come via __shfl_up/down; the
// 2 wave-edge columns via wave-uniform broadcast float4 loads (clamped when
// provably unused). Block keep = strict-greater-than-prefix-max AND
// geq-suffix-max in row-major order == first argmax (torch/jnp semantics).

#define IMG_H 1536
#define IMG_W 1536
#define N_IMG 16
#define SPANS 6      // 1536 / 256 col-spans per row-band
#define BROWS 512    // 1536 / 3 block-rows

typedef float __attribute__((ext_vector_type(4))) f32x4;

__global__ __launch_bounds__(256) void pool_nms_kernel(const float* __restrict__ x,
                                                       float* __restrict__ out) {
    const int lane = threadIdx.x & 63;
    const int wid  = blockIdx.x * 4 + (threadIdx.x >> 6);
    const int W  = wid % SPANS;          // col-span index
    const int t2 = wid / SPANS;
    const int R  = t2 & (BROWS - 1);     // block-row
    const int n  = t2 >> 9;              // image

    const size_t base = (size_t)n * (IMG_H * (size_t)IMG_W)
                      + (size_t)(R * 3) * IMG_W;
    const int c0 = W * 256;
    const float* px = x + base + c0;

    // Main loads: coalesced, lane l -> float4 at col 4l (per row).
    f32x4 own[3];
#pragma unroll
    for (int r = 0; r < 3; ++r)
        own[r] = *(const f32x4*)(px + (size_t)r * IMG_W + lane * 4);

    // Wave-edge columns: broadcast loads (same addr all lanes -> 1 txn).
    // Left needed only when c0%3!=0 (W in {1,2,4,5}), right only when
    // (c0+256)%3!=0 (W in {0,1,3,4}); clamped addresses are provably unused.
    const int cl = (W > 0) ? -4  : 0;
    const int cr = (W < 5) ? 256 : 252;
    f32x4 eL[3], eR[3];
#pragma unroll
    for (int r = 0; r < 3; ++r) {
        eL[r] = *(const f32x4*)(px + (size_t)r * IMG_W + cl);
        eR[r] = *(const f32x4*)(px + (size_t)r * IMG_W + cr);
    }

    // Per-row 8-col window: global cols [4l-2 .. 4l+5] relative to c0.
    float w[3][8];
#pragma unroll
    for (int r = 0; r < 3; ++r) {
        float Lz = __shfl_up(own[r].z, 1);
        float Lw = __shfl_up(own[r].w, 1);
        float Rx = __shfl_down(own[r].x, 1);
        float Ry = __shfl_down(own[r].y, 1);
        if (lane == 0)  { Lz = eL[r].z; Lw = eL[r].w; }
        if (lane == 63) { Rx = eR[r].x; Ry = eR[r].y; }
        w[r][0] = Lz;        w[r][1] = Lw;
        w[r][2] = own[r].x;  w[r][3] = own[r].y;
        w[r][4] = own[r].z;  w[r][5] = own[r].w;
        w[r][6] = Rx;        w[r][7] = Ry;
    }

    const int lm3 = lane % 3;
    float o_[3][4];
#pragma unroll
    for (int i = 0; i < 4; ++i) {
        // my col c = c0 + 4*lane + i;  c mod 3 = (lane + i + c0) mod 3,
        // and c0 = 256*W with 256 % 3 == 1 -> add W too.
        int m3 = lm3 + i + W;
        m3 = (m3 >= 3) ? m3 - 3 : m3;
        m3 = (m3 >= 3) ? m3 - 3 : m3;   // lm3+i+W <= 2+3+5=10? no: W<6 -> <=10
        m3 = (m3 >= 3) ? m3 - 3 : m3;   // three folds cover up to 11
        const bool s0 = (m3 == 0), s1 = (m3 == 1);

        // Block values, row-major. Block rel-start = (i+2) - m3.
        float b[9];
#pragma unroll
        for (int r = 0; r < 3; ++r)
#pragma unroll
            for (int j = 0; j < 3; ++j)
                b[3 * r + j] = s0 ? w[r][i + 2 + j]
                             : (s1 ? w[r][i + 1 + j] : w[r][i + j]);

        // prefix / suffix maxes (compile-time indices only)
        float pm[9], sm[9];
        pm[0] = -INFINITY;
#pragma unroll
        for (int k = 1; k < 9; ++k) pm[k] = fmaxf(pm[k - 1], b[k - 1]);
        sm[8] = -INFINITY;
#pragma unroll
        for (int k = 7; k >= 0; --k) sm[k] = fmaxf(sm[k + 1], b[k + 1]);

        bool kp[9];
#pragma unroll
        for (int k = 0; k < 9; ++k) kp[k] = (b[k] > pm[k]) && (b[k] >= sm[k]);

#pragma unroll
        for (int r = 0; r < 3; ++r) {
            const bool keep = s0 ? kp[3 * r] : (s1 ? kp[3 * r + 1] : kp[3 * r + 2]);
            o_[r][i] = keep ? w[r][i + 2] : 0.0f;
        }
    }

    float* po = out + base + c0;
#pragma unroll
    for (int r = 0; r < 3; ++r) {
        f32x4 v4 = { o_[r][0], o_[r][1], o_[r][2], o_[r][3] };
        *(f32x4*)(po + (size_t)r * IMG_W + lane * 4) = v4;
    }
}

extern "C" void kernel_launch(void* const* d_in, const int* in_sizes, int n_in,
                              void* d_out, int out_size, void* d_ws, size_t ws_size,
                              hipStream_t stream) {
    const float* x = (const float*)d_in[0];
    float* out = (float*)d_out;
    // waves = 16 images * 512 block-rows * 6 spans = 49152; 4 waves/WG
    const int n_wg = N_IMG * BROWS * SPANS / 4;   // 12288
    pool_nms_kernel<<<n_wg, 256, 0, stream>>>(x, out);
}